// Round 8
// baseline (266.848 us; speedup 1.0000x reference)
//
#include <hip/hip_runtime.h>

#define T_STEPS 100
#define BATCH   512
#define FIN     784
#define O1      100
#define O2      10
#define KC1     28      // K-chunk (784 = 28 * 28)
#define NC1     (FIN / KC1)

typedef __attribute__((ext_vector_type(4))) double f64x4;

// ---------------------------------------------------------------------------
// K1 v6: fused C-mean + f64 MFMA GEMM.
//   I1T[t][o][b] = sum_f 0.5*(in[b,t,f,0]+in[b,t,f,1]) * W1[f,o]
// Changes vs v5 (which was LDS-pipe-bound: 35 ds_reads per 28 MFMAs, 9.1M
// bank-conflict cy, W1 re-staged by all 800 blocks):
//  - W operand lives in REGISTERS as f32 (exact; one v_cvt_f64_f32 at use).
//    28 dword loads/lane/chunk from W1 (11 KB chunk, L1-hot, shared by all
//    waves on the CU). Issued BEFORE the input prefetch so the compute-phase
//    vmcnt wait for W never drains the HBM input loads (round-5 lesson).
//  - LDS = input tile only (AI[28][34], 7.6 KB). Compute-phase LDS reads
//    drop 5x; W staging writes gone.
//  - D-layout probe folded in (2 MFMAs at wave start; kills the k0 launch).
//  - 256-thr blocks (32 b-rows x 1 t), 1600 blocks; launch_bounds(256,4)
//    caps VGPR at 128 -> 4 blocks/CU = 16 waves/CU.
// Wave (wb=w&1, wo=w>>1): b-tile b0+16*wb; o-tiles {0,16,32,48} or {64,80,84}
// (84 overlaps 80-tile -> duplicate stores bitwise identical).
// ---------------------------------------------------------------------------
__global__ __launch_bounds__(256, 4) void k1_mfma(const float* __restrict__ in,
                                                  const float* __restrict__ W1,
                                                  double* __restrict__ I1T) {
  __shared__ double AI[KC1][34];    // [f-in-chunk][b]  C-meaned input
  const int tid = threadIdx.x;
  const int l   = tid & 63;
  const int w   = tid >> 6;
  const int wb  = w & 1;
  const int wo  = w >> 1;
  const int r16 = l & 15;
  const int q16 = l >> 4;
  const int b0  = (int)blockIdx.x * 32;
  const int t   = (int)blockIdx.y;

  // --- input staging descriptors: 448 float4/chunk over 256 threads ---
  bool iact[2]; int irow[2], iq[2]; const float* ibp[2];
#pragma unroll
  for (int p = 0; p < 2; ++p) {
    const int i = p * 256 + tid;
    iact[p] = (i < 448);
    irow[p] = iact[p] ? i / 14 : 0;
    iq[p]   = i - irow[p] * 14;
    ibp[p]  = in + ((size_t)(b0 + irow[p]) * T_STEPS + t) * (FIN * 2) + iq[p] * 4;
  }

  // prologue: issue chunk-0 input loads (latency hidden under the probe)
  float4 ist[2];
#pragma unroll
  for (int p = 0; p < 2; ++p) if (iact[p]) ist[p] = *reinterpret_cast<const float4*>(ibp[p]);

  // --- in-kernel D-layout probe (validated rounds 3-7) ---
  const f64x4 z = {0.0, 0.0, 0.0, 0.0};
  f64x4 pr = __builtin_amdgcn_mfma_f64_16x16x4f64((double)r16, 0.25, z, 0, 0, 0);
  f64x4 pc = __builtin_amdgcn_mfma_f64_16x16x4f64(0.25, (double)r16, z, 0, 0, 0);
  int rmv[4], cmv[4];
#pragma unroll
  for (int r = 0; r < 4; ++r) {
    int rm = (int)(pr[r] + 0.5); rmv[r] = rm < 0 ? 0 : (rm > 15 ? 15 : rm);
    int cm = (int)(pc[r] + 0.5); cmv[r] = cm < 0 ? 0 : (cm > 15 ? 15 : cm);
  }

  f64x4 acc0 = {0.0, 0.0, 0.0, 0.0};
  f64x4 acc1 = {0.0, 0.0, 0.0, 0.0};
  f64x4 acc2 = {0.0, 0.0, 0.0, 0.0};
  f64x4 acc3 = {0.0, 0.0, 0.0, 0.0};

  // per-wave W base: row q16, col r16 (+64 for wo=1)
  const float* pW0 = W1 + (size_t)q16 * O1 + r16 + (wo ? 64 : 0);

  for (int c = 0; c < NC1; ++c) {
    __syncthreads();   // previous chunk's compute done before LDS rewrite
    // ds_write chunk c from regs (exact f64 C-mean)
#pragma unroll
    for (int p = 0; p < 2; ++p)
      if (iact[p]) {
        AI[iq[p] * 2 + 0][irow[p]] = 0.5 * ((double)ist[p].x + (double)ist[p].y);
        AI[iq[p] * 2 + 1][irow[p]] = 0.5 * ((double)ist[p].z + (double)ist[p].w);
      }
    // W(c) loads FIRST (L1-hot; consumed right after the barrier)...
    float wreg[7][4];
    const float* pWc = pW0 + (size_t)c * (KC1 * O1);
    if (wo == 0) {
#pragma unroll
      for (int q = 0; q < 7; ++q) {
        wreg[q][0] = pWc[q * 400 +  0];
        wreg[q][1] = pWc[q * 400 + 16];
        wreg[q][2] = pWc[q * 400 + 32];
        wreg[q][3] = pWc[q * 400 + 48];
      }
    } else {
#pragma unroll
      for (int q = 0; q < 7; ++q) {
        wreg[q][0] = pWc[q * 400 +  0];
        wreg[q][1] = pWc[q * 400 + 16];
        wreg[q][2] = pWc[q * 400 + 20];
      }
    }
    // ...THEN the next input tile (HBM, fire-and-forget; younger than W in
    // the vmcnt queue so waiting on W never drains it)
    if (c + 1 < NC1) {
#pragma unroll
      for (int p = 0; p < 2; ++p)
        if (iact[p]) ist[p] = *reinterpret_cast<const float4*>(ibp[p] + (c + 1) * 56);
    }
    __syncthreads();   // chunk c visible in LDS
    // compute chunk c: 7 ds_read_b64 + 28(21) MFMA, W from regs
    if (wo == 0) {
#pragma unroll
      for (int q = 0; q < 7; ++q) {
        const double bv = AI[q * 4 + q16][wb * 16 + r16];
        acc0 = __builtin_amdgcn_mfma_f64_16x16x4f64((double)wreg[q][0], bv, acc0, 0, 0, 0);
        acc1 = __builtin_amdgcn_mfma_f64_16x16x4f64((double)wreg[q][1], bv, acc1, 0, 0, 0);
        acc2 = __builtin_amdgcn_mfma_f64_16x16x4f64((double)wreg[q][2], bv, acc2, 0, 0, 0);
        acc3 = __builtin_amdgcn_mfma_f64_16x16x4f64((double)wreg[q][3], bv, acc3, 0, 0, 0);
      }
    } else {
#pragma unroll
      for (int q = 0; q < 7; ++q) {
        const double bv = AI[q * 4 + q16][wb * 16 + r16];
        acc0 = __builtin_amdgcn_mfma_f64_16x16x4f64((double)wreg[q][0], bv, acc0, 0, 0, 0);
        acc1 = __builtin_amdgcn_mfma_f64_16x16x4f64((double)wreg[q][1], bv, acc1, 0, 0, 0);
        acc2 = __builtin_amdgcn_mfma_f64_16x16x4f64((double)wreg[q][2], bv, acc2, 0, 0, 0);
      }
    }
  }

  double* base = I1T + (size_t)t * O1 * BATCH + (b0 + wb * 16);
#define STORE_TILE(ACC, O0)                                               \
  {                                                                       \
    base[(size_t)((O0) + rmv[0]) * BATCH + cmv[0]] = (ACC)[0];            \
    base[(size_t)((O0) + rmv[1]) * BATCH + cmv[1]] = (ACC)[1];            \
    base[(size_t)((O0) + rmv[2]) * BATCH + cmv[2]] = (ACC)[2];            \
    base[(size_t)((O0) + rmv[3]) * BATCH + cmv[3]] = (ACC)[3];            \
  }
  if (wo == 0) {
    STORE_TILE(acc0, 0);
    STORE_TILE(acc1, 16);
    STORE_TILE(acc2, 32);
    STORE_TILE(acc3, 48);
  } else {
    STORE_TILE(acc0, 64);
    STORE_TILE(acc1, 80);
    STORE_TILE(acc2, 84);
  }
#undef STORE_TILE
}

// ---------------------------------------------------------------------------
// K2: BN stats per (t,o) row: mu, rstd. One wave per row.
// ---------------------------------------------------------------------------
__global__ __launch_bounds__(256) void k2_bnstats(const double* __restrict__ I1T,
                                                  double* __restrict__ mu,
                                                  double* __restrict__ rstd) {
  const int r    = blockIdx.x * 4 + (threadIdx.x >> 6);
  const int lane = threadIdx.x & 63;
  const double2* row2 = reinterpret_cast<const double2*>(I1T + (size_t)r * BATCH) + lane * 4;
  double v[8];
#pragma unroll
  for (int u = 0; u < 4; ++u) {
    double2 p = row2[u];
    v[2 * u] = p.x; v[2 * u + 1] = p.y;
  }
  double s = 0.0;
#pragma unroll
  for (int u = 0; u < 8; ++u) s += v[u];
#pragma unroll
  for (int m = 32; m >= 1; m >>= 1) s += __shfl_xor(s, m, 64);
  const double mean = s / 512.0;
  double q = 0.0;
#pragma unroll
  for (int u = 0; u < 8; ++u) { double d = v[u] - mean; q += d * d; }
#pragma unroll
  for (int m = 32; m >= 1; m >>= 1) q += __shfl_xor(q, m, 64);
  if (lane == 0) {
    mu[r]   = mean;
    rstd[r] = 1.0 / sqrt(q / 512.0 + 1e-5);
  }
}

// ---------------------------------------------------------------------------
// K3: layer-1 LIF scan. Block = o, thread = b.
// ---------------------------------------------------------------------------
__global__ __launch_bounds__(512) void k3_lif1(const double* __restrict__ I1T,
                                               const double* __restrict__ mu,
                                               const double* __restrict__ rstd,
                                               const float* __restrict__ scale,
                                               const float* __restrict__ bias,
                                               float* __restrict__ z1T) {
  const int o = blockIdx.x;
  const int b = threadIdx.x;
  const double sc = (double)scale[o], bs = (double)bias[o];
  double v = 0.0;
  for (int tc = 0; tc < T_STEPS; tc += 10) {
    double x[10], muv[10], rsv[10];
#pragma unroll
    for (int u = 0; u < 10; ++u) {
      const int t = tc + u;
      x[u]   = I1T[((size_t)t * O1 + o) * BATCH + b];
      muv[u] = mu[t * O1 + o];
      rsv[u] = rstd[t * O1 + o];
    }
#pragma unroll
    for (int u = 0; u < 10; ++u) {
      const double i = ((x[u] - muv[u]) * rsv[u]) * sc + bs;
      v = 0.95 * v + i;
      const bool z = (v > 1.0);
      z1T[((size_t)(tc + u) * O1 + o) * BATCH + b] = z ? 1.0f : 0.0f;
      if (z) v = 0.0;
    }
  }
}

// ---------------------------------------------------------------------------
// K4: I2[t][j][b] = sum_o z1T[t][o][b] * W2[o][j].
// ---------------------------------------------------------------------------
__global__ __launch_bounds__(512) void k4_proj2(const float* __restrict__ z1T,
                                                const float* __restrict__ W2,
                                                double* __restrict__ I2) {
  __shared__ double W2_lds[O1 * O2];
  const int t = blockIdx.x;
  const int b = threadIdx.x;
  for (int i = threadIdx.x; i < O1 * O2; i += 512) W2_lds[i] = (double)W2[i];
  __syncthreads();
  double acc[O2];
#pragma unroll
  for (int j = 0; j < O2; ++j) acc[j] = 0.0;
  for (int o = 0; o < O1; ++o) {
    const double z = (double)z1T[((size_t)t * O1 + o) * BATCH + b];
#pragma unroll
    for (int j = 0; j < O2; ++j) acc[j] += z * W2_lds[o * O2 + j];
  }
#pragma unroll
  for (int j = 0; j < O2; ++j)
    I2[((size_t)t * O2 + j) * BATCH + b] = acc[j];
}

// ---------------------------------------------------------------------------
// K5: layer-2 LIF scan + time-mean.
// ---------------------------------------------------------------------------
__global__ __launch_bounds__(512) void k5_lif2(const double* __restrict__ I2,
                                               float* __restrict__ out) {
  const int j = blockIdx.x;
  const int b = threadIdx.x;
  double v = 0.0;
  int cnt = 0;
  for (int tc = 0; tc < T_STEPS; tc += 10) {
    double x[10];
#pragma unroll
    for (int u = 0; u < 10; ++u)
      x[u] = I2[((size_t)(tc + u) * O2 + j) * BATCH + b];
#pragma unroll
    for (int u = 0; u < 10; ++u) {
      v = 0.95 * v + x[u];
      if (v > 1.0) { ++cnt; v = 0.0; }
    }
  }
  out[b * O2 + j] = (float)((double)cnt / 100.0);
}

// ---------------------------------------------------------------------------
extern "C" void kernel_launch(void* const* d_in, const int* in_sizes, int n_in,
                              void* d_out, int out_size, void* d_ws, size_t ws_size,
                              hipStream_t stream) {
  const float* in    = (const float*)d_in[0];
  const float* W1    = (const float*)d_in[2];
  const float* scale = (const float*)d_in[3];
  const float* bias  = (const float*)d_in[4];
  const float* W2    = (const float*)d_in[5];
  float* out = (float*)d_out;

  char* ws = (char*)d_ws;
  size_t off = 0;
  double* I1T  = (double*)(ws + off); off += (size_t)T_STEPS * O1 * BATCH * sizeof(double);
  double* mu   = (double*)(ws + off); off += (size_t)T_STEPS * O1 * sizeof(double);
  double* rstd = (double*)(ws + off); off += (size_t)T_STEPS * O1 * sizeof(double);
  float*  z1T  = (float*)(ws + off);  off += (size_t)T_STEPS * O1 * BATCH * sizeof(float);
  double* I2   = (double*)(ws + off); off += (size_t)T_STEPS * O2 * BATCH * sizeof(double);

  k1_mfma   <<<dim3(BATCH / 32, T_STEPS), 256, 0, stream>>>(in, W1, I1T);
  k2_bnstats<<<dim3(T_STEPS * O1 / 4), 256, 0, stream>>>(I1T, mu, rstd);
  k3_lif1   <<<dim3(O1), 512, 0, stream>>>(I1T, mu, rstd, scale, bias, z1T);
  k4_proj2  <<<dim3(T_STEPS), 512, 0, stream>>>(z1T, W2, I2);
  k5_lif2   <<<dim3(O2), 512, 0, stream>>>(I2, out);
}

// Round 9
// 265.489 us; speedup vs baseline: 1.0051x; 1.0051x over previous
//
#include <hip/hip_runtime.h>

#define T_STEPS 100
#define BATCH   512
#define FIN     784
#define O1      100
#define O2      10
#define KC1     28      // K-chunk (784 = 28 * 28)
#define NC1     (FIN / KC1)

typedef __attribute__((ext_vector_type(4))) double f64x4;

// Raw block barrier WITHOUT the __syncthreads vmcnt(0) drain: drains only
// LDS (lgkmcnt) so in-flight global prefetch loads survive the barrier.
// sched_barrier(0) on both sides pins DS ops to their side of the barrier.
__device__ __forceinline__ void block_sync_lds() {
  __builtin_amdgcn_sched_barrier(0);
  asm volatile("s_waitcnt lgkmcnt(0)" ::: "memory");
  __builtin_amdgcn_s_barrier();
  __builtin_amdgcn_sched_barrier(0);
}

// ---------------------------------------------------------------------------
// K1 v7: fused C-mean + f64 MFMA GEMM.
//   I1T[t][o][b] = sum_f 0.5*(in[b,t,f,0]+in[b,t,f,1]) * W1[f,o]
// v6 post-mortem: __syncthreads emits s_waitcnt vmcnt(0) before s_barrier,
// so the c+1 HBM prefetch (issued right before barrier #2) was fully drained
// every chunk -> ~900 cy stall/chunk -> MfmaUtil ~50%. v7 keeps v6's exact
// structure but uses raw lgkm-only barriers: prefetch stays in flight across
// the barrier and lands during the compute phase; its vmcnt is only waited
// at next chunk's ds_write. W loads issued BEFORE input prefetch (older in
// the vmcnt queue) so the compute-phase W-wait never drains the input.
// ---------------------------------------------------------------------------
__global__ __launch_bounds__(256, 4) void k1_mfma(const float* __restrict__ in,
                                                  const float* __restrict__ W1,
                                                  double* __restrict__ I1T) {
  __shared__ double AI[KC1][34];    // [f-in-chunk][b]  C-meaned input
  const int tid = threadIdx.x;
  const int l   = tid & 63;
  const int w   = tid >> 6;
  const int wb  = w & 1;
  const int wo  = w >> 1;
  const int r16 = l & 15;
  const int q16 = l >> 4;
  const int b0  = (int)blockIdx.x * 32;
  const int t   = (int)blockIdx.y;

  // --- input staging descriptors: 448 float4/chunk over 256 threads ---
  bool iact[2]; int irow[2], iq[2]; const float* ibp[2];
#pragma unroll
  for (int p = 0; p < 2; ++p) {
    const int i = p * 256 + tid;
    iact[p] = (i < 448);
    irow[p] = iact[p] ? i / 14 : 0;
    iq[p]   = i - irow[p] * 14;
    ibp[p]  = in + ((size_t)(b0 + irow[p]) * T_STEPS + t) * (FIN * 2) + iq[p] * 4;
  }

  // prologue: issue chunk-0 input loads (latency hidden under the probe)
  float4 ist[2];
#pragma unroll
  for (int p = 0; p < 2; ++p) if (iact[p]) ist[p] = *reinterpret_cast<const float4*>(ibp[p]);

  // --- in-kernel D-layout probe (validated rounds 3-8) ---
  const f64x4 z = {0.0, 0.0, 0.0, 0.0};
  f64x4 pr = __builtin_amdgcn_mfma_f64_16x16x4f64((double)r16, 0.25, z, 0, 0, 0);
  f64x4 pc = __builtin_amdgcn_mfma_f64_16x16x4f64(0.25, (double)r16, z, 0, 0, 0);
  int rmv[4], cmv[4];
#pragma unroll
  for (int r = 0; r < 4; ++r) {
    int rm = (int)(pr[r] + 0.5); rmv[r] = rm < 0 ? 0 : (rm > 15 ? 15 : rm);
    int cm = (int)(pc[r] + 0.5); cmv[r] = cm < 0 ? 0 : (cm > 15 ? 15 : cm);
  }

  f64x4 acc0 = {0.0, 0.0, 0.0, 0.0};
  f64x4 acc1 = {0.0, 0.0, 0.0, 0.0};
  f64x4 acc2 = {0.0, 0.0, 0.0, 0.0};
  f64x4 acc3 = {0.0, 0.0, 0.0, 0.0};

  // per-wave W base: row q16, col r16 (+64 for wo=1)
  const float* pW0 = W1 + (size_t)q16 * O1 + r16 + (wo ? 64 : 0);

  for (int c = 0; c < NC1; ++c) {
    block_sync_lds();   // previous chunk's compute reads done before rewrite
    // ds_write chunk c from regs (exact f64 C-mean); compiler inserts the
    // vmcnt wait for ist here (issued a full chunk ago -> already landed)
#pragma unroll
    for (int p = 0; p < 2; ++p)
      if (iact[p]) {
        AI[iq[p] * 2 + 0][irow[p]] = 0.5 * ((double)ist[p].x + (double)ist[p].y);
        AI[iq[p] * 2 + 1][irow[p]] = 0.5 * ((double)ist[p].z + (double)ist[p].w);
      }
    // W(c) loads FIRST (L1-hot; consumed right after the barrier)...
    float wreg[7][4];
    const float* pWc = pW0 + (size_t)c * (KC1 * O1);
    if (wo == 0) {
#pragma unroll
      for (int q = 0; q < 7; ++q) {
        wreg[q][0] = pWc[q * 400 +  0];
        wreg[q][1] = pWc[q * 400 + 16];
        wreg[q][2] = pWc[q * 400 + 32];
        wreg[q][3] = pWc[q * 400 + 48];
      }
    } else {
#pragma unroll
      for (int q = 0; q < 7; ++q) {
        wreg[q][0] = pWc[q * 400 +  0];
        wreg[q][1] = pWc[q * 400 + 16];
        wreg[q][2] = pWc[q * 400 + 20];
      }
    }
    // ...THEN the next input tile (HBM, fire-and-forget; younger than W in
    // the vmcnt queue so waiting on W never drains it). Stays in flight
    // across the raw barrier and lands under the compute phase.
    if (c + 1 < NC1) {
#pragma unroll
      for (int p = 0; p < 2; ++p)
        if (iact[p]) ist[p] = *reinterpret_cast<const float4*>(ibp[p] + (c + 1) * 56);
    }
    block_sync_lds();   // chunk c visible in LDS; vmem NOT drained
    // compute chunk c: 7 ds_read_b64 + 28(21) MFMA, W from regs
    if (wo == 0) {
#pragma unroll
      for (int q = 0; q < 7; ++q) {
        const double bv = AI[q * 4 + q16][wb * 16 + r16];
        acc0 = __builtin_amdgcn_mfma_f64_16x16x4f64((double)wreg[q][0], bv, acc0, 0, 0, 0);
        acc1 = __builtin_amdgcn_mfma_f64_16x16x4f64((double)wreg[q][1], bv, acc1, 0, 0, 0);
        acc2 = __builtin_amdgcn_mfma_f64_16x16x4f64((double)wreg[q][2], bv, acc2, 0, 0, 0);
        acc3 = __builtin_amdgcn_mfma_f64_16x16x4f64((double)wreg[q][3], bv, acc3, 0, 0, 0);
      }
    } else {
#pragma unroll
      for (int q = 0; q < 7; ++q) {
        const double bv = AI[q * 4 + q16][wb * 16 + r16];
        acc0 = __builtin_amdgcn_mfma_f64_16x16x4f64((double)wreg[q][0], bv, acc0, 0, 0, 0);
        acc1 = __builtin_amdgcn_mfma_f64_16x16x4f64((double)wreg[q][1], bv, acc1, 0, 0, 0);
        acc2 = __builtin_amdgcn_mfma_f64_16x16x4f64((double)wreg[q][2], bv, acc2, 0, 0, 0);
      }
    }
  }

  double* base = I1T + (size_t)t * O1 * BATCH + (b0 + wb * 16);
#define STORE_TILE(ACC, O0)                                               \
  {                                                                       \
    base[(size_t)((O0) + rmv[0]) * BATCH + cmv[0]] = (ACC)[0];            \
    base[(size_t)((O0) + rmv[1]) * BATCH + cmv[1]] = (ACC)[1];            \
    base[(size_t)((O0) + rmv[2]) * BATCH + cmv[2]] = (ACC)[2];            \
    base[(size_t)((O0) + rmv[3]) * BATCH + cmv[3]] = (ACC)[3];            \
  }
  if (wo == 0) {
    STORE_TILE(acc0, 0);
    STORE_TILE(acc1, 16);
    STORE_TILE(acc2, 32);
    STORE_TILE(acc3, 48);
  } else {
    STORE_TILE(acc0, 64);
    STORE_TILE(acc1, 80);
    STORE_TILE(acc2, 84);
  }
#undef STORE_TILE
}

// ---------------------------------------------------------------------------
// K2: BN stats per (t,o) row: mu, rstd. One wave per row.
// ---------------------------------------------------------------------------
__global__ __launch_bounds__(256) void k2_bnstats(const double* __restrict__ I1T,
                                                  double* __restrict__ mu,
                                                  double* __restrict__ rstd) {
  const int r    = blockIdx.x * 4 + (threadIdx.x >> 6);
  const int lane = threadIdx.x & 63;
  const double2* row2 = reinterpret_cast<const double2*>(I1T + (size_t)r * BATCH) + lane * 4;
  double v[8];
#pragma unroll
  for (int u = 0; u < 4; ++u) {
    double2 p = row2[u];
    v[2 * u] = p.x; v[2 * u + 1] = p.y;
  }
  double s = 0.0;
#pragma unroll
  for (int u = 0; u < 8; ++u) s += v[u];
#pragma unroll
  for (int m = 32; m >= 1; m >>= 1) s += __shfl_xor(s, m, 64);
  const double mean = s / 512.0;
  double q = 0.0;
#pragma unroll
  for (int u = 0; u < 8; ++u) { double d = v[u] - mean; q += d * d; }
#pragma unroll
  for (int m = 32; m >= 1; m >>= 1) q += __shfl_xor(q, m, 64);
  if (lane == 0) {
    mu[r]   = mean;
    rstd[r] = 1.0 / sqrt(q / 512.0 + 1e-5);
  }
}

// ---------------------------------------------------------------------------
// K3: layer-1 LIF scan. Block = o, thread = b.
// ---------------------------------------------------------------------------
__global__ __launch_bounds__(512) void k3_lif1(const double* __restrict__ I1T,
                                               const double* __restrict__ mu,
                                               const double* __restrict__ rstd,
                                               const float* __restrict__ scale,
                                               const float* __restrict__ bias,
                                               float* __restrict__ z1T) {
  const int o = blockIdx.x;
  const int b = threadIdx.x;
  const double sc = (double)scale[o], bs = (double)bias[o];
  double v = 0.0;
  for (int tc = 0; tc < T_STEPS; tc += 10) {
    double x[10], muv[10], rsv[10];
#pragma unroll
    for (int u = 0; u < 10; ++u) {
      const int t = tc + u;
      x[u]   = I1T[((size_t)t * O1 + o) * BATCH + b];
      muv[u] = mu[t * O1 + o];
      rsv[u] = rstd[t * O1 + o];
    }
#pragma unroll
    for (int u = 0; u < 10; ++u) {
      const double i = ((x[u] - muv[u]) * rsv[u]) * sc + bs;
      v = 0.95 * v + i;
      const bool z = (v > 1.0);
      z1T[((size_t)(tc + u) * O1 + o) * BATCH + b] = z ? 1.0f : 0.0f;
      if (z) v = 0.0;
    }
  }
}

// ---------------------------------------------------------------------------
// K4: I2[t][j][b] = sum_o z1T[t][o][b] * W2[o][j].
// ---------------------------------------------------------------------------
__global__ __launch_bounds__(512) void k4_proj2(const float* __restrict__ z1T,
                                                const float* __restrict__ W2,
                                                double* __restrict__ I2) {
  __shared__ double W2_lds[O1 * O2];
  const int t = blockIdx.x;
  const int b = threadIdx.x;
  for (int i = threadIdx.x; i < O1 * O2; i += 512) W2_lds[i] = (double)W2[i];
  __syncthreads();
  double acc[O2];
#pragma unroll
  for (int j = 0; j < O2; ++j) acc[j] = 0.0;
  for (int o = 0; o < O1; ++o) {
    const double z = (double)z1T[((size_t)t * O1 + o) * BATCH + b];
#pragma unroll
    for (int j = 0; j < O2; ++j) acc[j] += z * W2_lds[o * O2 + j];
  }
#pragma unroll
  for (int j = 0; j < O2; ++j)
    I2[((size_t)t * O2 + j) * BATCH + b] = acc[j];
}

// ---------------------------------------------------------------------------
// K5: layer-2 LIF scan + time-mean.
// ---------------------------------------------------------------------------
__global__ __launch_bounds__(512) void k5_lif2(const double* __restrict__ I2,
                                               float* __restrict__ out) {
  const int j = blockIdx.x;
  const int b = threadIdx.x;
  double v = 0.0;
  int cnt = 0;
  for (int tc = 0; tc < T_STEPS; tc += 10) {
    double x[10];
#pragma unroll
    for (int u = 0; u < 10; ++u)
      x[u] = I2[((size_t)(tc + u) * O2 + j) * BATCH + b];
#pragma unroll
    for (int u = 0; u < 10; ++u) {
      v = 0.95 * v + x[u];
      if (v > 1.0) { ++cnt; v = 0.0; }
    }
  }
  out[b * O2 + j] = (float)((double)cnt / 100.0);
}

// ---------------------------------------------------------------------------
extern "C" void kernel_launch(void* const* d_in, const int* in_sizes, int n_in,
                              void* d_out, int out_size, void* d_ws, size_t ws_size,
                              hipStream_t stream) {
  const float* in    = (const float*)d_in[0];
  const float* W1    = (const float*)d_in[2];
  const float* scale = (const float*)d_in[3];
  const float* bias  = (const float*)d_in[4];
  const float* W2    = (const float*)d_in[5];
  float* out = (float*)d_out;

  char* ws = (char*)d_ws;
  size_t off = 0;
  double* I1T  = (double*)(ws + off); off += (size_t)T_STEPS * O1 * BATCH * sizeof(double);
  double* mu   = (double*)(ws + off); off += (size_t)T_STEPS * O1 * sizeof(double);
  double* rstd = (double*)(ws + off); off += (size_t)T_STEPS * O1 * sizeof(double);
  float*  z1T  = (float*)(ws + off);  off += (size_t)T_STEPS * O1 * BATCH * sizeof(float);
  double* I2   = (double*)(ws + off); off += (size_t)T_STEPS * O2 * BATCH * sizeof(double);

  k1_mfma   <<<dim3(BATCH / 32, T_STEPS), 256, 0, stream>>>(in, W1, I1T);
  k2_bnstats<<<dim3(T_STEPS * O1 / 4), 256, 0, stream>>>(I1T, mu, rstd);
  k3_lif1   <<<dim3(O1), 512, 0, stream>>>(I1T, mu, rstd, scale, bias, z1T);
  k4_proj2  <<<dim3(T_STEPS), 512, 0, stream>>>(z1T, W2, I2);
  k5_lif2   <<<dim3(O2), 512, 0, stream>>>(I2, out);
}